// Round 1
// baseline (365.167 us; speedup 1.0000x reference)
//
#include <hip/hip_runtime.h>

#define N_HITS 4000000
#define N_SHOWERS 10000
#define NUM_SEGMENTS (N_SHOWERS + 1)

// ---------------------------------------------------------------------------
// Workspace layout (d_ws, re-poisoned 0xAA before every launch):
//   [0, 160016)            : float4 vals[NUM_SEGMENTS]  (written fully by corr_kernel)
//   [160032, 200036)       : float  e_hit_shower[NUM_SEGMENTS]   (zeroed)
//   [200036, 240040)       : float  e_track_shower[NUM_SEGMENTS] (zeroed, contiguous after e_hit)
// ---------------------------------------------------------------------------

__global__ void zero_kernel(float* __restrict__ p, int n) {
    int i = blockIdx.x * blockDim.x + threadIdx.x;
    if (i < n) p[i] = 0.0f;
}

__global__ void scatter_kernel(const int* __restrict__ sid,
                               const float* __restrict__ energy,
                               const int* __restrict__ rid,
                               float* __restrict__ e_hit_sh,
                               float* __restrict__ e_track_sh) {
    int i = blockIdx.x * blockDim.x + threadIdx.x;
    if (i >= N_HITS) return;
    int s = sid[i];
    if (s < 0) return;                 // noise: energy forced to 0, seg 0 stays 0
    float e = energy[i];
    if (rid[i] == 0) atomicAdd(&e_hit_sh[s + 1], e);
    else             atomicAdd(&e_track_sh[s + 1], e);
}

__global__ void corr_kernel(const int* __restrict__ sid,
                            const float* __restrict__ pcf,
                            const int* __restrict__ a_tracks,
                            const int* __restrict__ a_hits,
                            const float* __restrict__ e_hit_sh,
                            const float* __restrict__ e_track_sh,
                            float4* __restrict__ vals) {
    int s = blockIdx.x * blockDim.x + threadIdx.x;   // segment index 0..10000
    if (s >= NUM_SEGMENTS) return;
    float ch = 0.0f, ct = 0.0f;
    if (s > 0) {
        int ih = a_hits[s - 1];
        if (ih < N_HITS && sid[ih] != -1) ch = pcf[ih];   // pcf_ext pad + noise mask
        int it = a_tracks[s - 1];
        if (it < N_HITS && sid[it] != -1) ct = pcf[it];
    }
    float eh = e_hit_sh[s];
    float et = e_track_sh[s];
    vals[s] = make_float4(et, et * ct, eh, eh * ch);
}

__global__ void gather_kernel(const int* __restrict__ sid,
                              const float4* __restrict__ vals,
                              float* __restrict__ out) {
    int i = blockIdx.x * blockDim.x + threadIdx.x;
    if (i >= N_HITS) return;
    int seg = sid[i] + 1;
    float4 v = vals[seg];              // 160 KB table -> L2-resident random read
    out[i]                = v.x;       // e_track_raw
    out[N_HITS + i]       = v.y;       // e_track_corrected
    out[2 * N_HITS + i]   = v.z;       // e_hit_raw
    out[3 * N_HITS + i]   = v.w;       // e_hit_corrected
}

extern "C" void kernel_launch(void* const* d_in, const int* in_sizes, int n_in,
                              void* d_out, int out_size, void* d_ws, size_t ws_size,
                              hipStream_t stream) {
    const int*   pred_sid = (const int*)  d_in[0];
    const float* pcf      = (const float*)d_in[1];
    const float* energy   = (const float*)d_in[2];
    const int*   rid      = (const int*)  d_in[3];
    // d_in[4] = pred_beta (unused by the reference)
    const int*   a_tracks = (const int*)  d_in[5];
    const int*   a_hits   = (const int*)  d_in[6];
    float*       out      = (float*)      d_out;

    char* ws = (char*)d_ws;
    float4* vals      = (float4*)ws;
    float*  e_hit_sh  = (float*)(ws + 160032);
    float*  e_track_sh = e_hit_sh + NUM_SEGMENTS;

    // 1) zero the two accumulator arrays (contiguous 2*NUM_SEGMENTS floats)
    {
        int n = 2 * NUM_SEGMENTS;
        zero_kernel<<<(n + 255) / 256, 256, 0, stream>>>(e_hit_sh, n);
    }
    // 2) atomic segment-sum
    scatter_kernel<<<(N_HITS + 255) / 256, 256, 0, stream>>>(
        pred_sid, energy, rid, e_hit_sh, e_track_sh);
    // 3) per-shower correction + packing
    corr_kernel<<<(NUM_SEGMENTS + 255) / 256, 256, 0, stream>>>(
        pred_sid, pcf, a_tracks, a_hits, e_hit_sh, e_track_sh, vals);
    // 4) gather into the 4 output streams
    gather_kernel<<<(N_HITS + 255) / 256, 256, 0, stream>>>(
        pred_sid, vals, out);
}

// Round 5
// 349.687 us; speedup vs baseline: 1.0443x; 1.0443x over previous
//
#include <hip/hip_runtime.h>

#define N_HITS 4000000
#define N_QUADS (N_HITS / 4)
#define N_SHOWERS 10000
#define NUM_SEGMENTS (N_SHOWERS + 1)
#define ACC_STRIDE (2 * NUM_SEGMENTS)   // floats per replica: [hit | track]
#define MAX_R 64

// ---------------------------------------------------------------------------
// Workspace layout (d_ws, re-poisoned 0xAA before every launch):
//   [0, 160016)          : float4 vals[NUM_SEGMENTS] (fully written by corr)
//   [160064, ...)        : float acc[R][2][NUM_SEGMENTS]  (zeroed each call)
// R = min(MAX_R, (ws_size-160064)/(ACC_STRIDE*4)), computed identically every
// call (deterministic — no call-count dependence).
// ---------------------------------------------------------------------------

__global__ void zero_kernel(float* __restrict__ p, int n) {
    int i = blockIdx.x * blockDim.x + threadIdx.x;
    if (i < n) p[i] = 0.0f;
}

__global__ void scatter_kernel(const int4* __restrict__ sid4,
                               const float4* __restrict__ e4,
                               const int4* __restrict__ rid4,
                               float* __restrict__ acc, int R) {
    int t = blockIdx.x * blockDim.x + threadIdx.x;
    if (t >= N_QUADS) return;
    float* __restrict__ a = acc + (size_t)(blockIdx.x % R) * ACC_STRIDE;
    int4   s = sid4[t];
    float4 e = e4[t];
    int4   r = rid4[t];
    // kind: rid==0 -> hit half [0,NUM_SEGMENTS), rid==1 -> track half
    if (s.x >= 0) atomicAdd(&a[r.x * NUM_SEGMENTS + s.x + 1], e.x);
    if (s.y >= 0) atomicAdd(&a[r.y * NUM_SEGMENTS + s.y + 1], e.y);
    if (s.z >= 0) atomicAdd(&a[r.z * NUM_SEGMENTS + s.z + 1], e.z);
    if (s.w >= 0) atomicAdd(&a[r.w * NUM_SEGMENTS + s.w + 1], e.w);
}

__global__ void corr_kernel(const int* __restrict__ sid,
                            const float* __restrict__ pcf,
                            const int* __restrict__ a_tracks,
                            const int* __restrict__ a_hits,
                            const float* __restrict__ acc, int R,
                            float4* __restrict__ vals) {
    int s = blockIdx.x * blockDim.x + threadIdx.x;   // 0..NUM_SEGMENTS-1
    if (s >= NUM_SEGMENTS) return;
    float eh = 0.0f, et = 0.0f;
    for (int r = 0; r < R; ++r) {                    // coalesced across threads
        eh += acc[(size_t)r * ACC_STRIDE + s];
        et += acc[(size_t)r * ACC_STRIDE + NUM_SEGMENTS + s];
    }
    float ch = 0.0f, ct = 0.0f;
    if (s > 0) {
        int ih = a_hits[s - 1];                      // in [0, N_HITS]
        if (ih < N_HITS && sid[ih] != -1) ch = pcf[ih];
        int it = a_tracks[s - 1];
        if (it < N_HITS && sid[it] != -1) ct = pcf[it];
    }
    vals[s] = make_float4(et, et * ct, eh, eh * ch);
}

__global__ void gather_kernel(const int4* __restrict__ sid4,
                              const float4* __restrict__ vals,
                              float4* __restrict__ out) {
    int t = blockIdx.x * blockDim.x + threadIdx.x;
    if (t >= N_QUADS) return;
    int4 s = sid4[t];
    float4 a = vals[s.x + 1];
    float4 b = vals[s.y + 1];
    float4 c = vals[s.z + 1];
    float4 d = vals[s.w + 1];
    out[t]               = make_float4(a.x, b.x, c.x, d.x);  // e_track_raw
    out[N_QUADS + t]     = make_float4(a.y, b.y, c.y, d.y);  // e_track_corrected
    out[2 * N_QUADS + t] = make_float4(a.z, b.z, c.z, d.z);  // e_hit_raw
    out[3 * N_QUADS + t] = make_float4(a.w, b.w, c.w, d.w);  // e_hit_corrected
}

extern "C" void kernel_launch(void* const* d_in, const int* in_sizes, int n_in,
                              void* d_out, int out_size, void* d_ws, size_t ws_size,
                              hipStream_t stream) {
    const int*   pred_sid = (const int*)  d_in[0];
    const float* pcf      = (const float*)d_in[1];
    const float* energy   = (const float*)d_in[2];
    const int*   rid      = (const int*)  d_in[3];
    // d_in[4] = pred_beta (unused)
    const int*   a_tracks = (const int*)  d_in[5];
    const int*   a_hits   = (const int*)  d_in[6];

    char* ws = (char*)d_ws;
    float4* vals = (float4*)ws;
    float*  acc  = (float*)(ws + 160064);

    int R = 1;
    if (ws_size > 160064) {
        size_t r = (ws_size - 160064) / ((size_t)ACC_STRIDE * sizeof(float));
        R = (int)(r < MAX_R ? r : MAX_R);
        if (R < 1) R = 1;
    }

    // 1) zero the replicated accumulators
    {
        int n = R * ACC_STRIDE;
        zero_kernel<<<(n + 255) / 256, 256, 0, stream>>>(acc, n);
    }
    // 2) replicated atomic segment-sum (4 hits per thread)
    scatter_kernel<<<(N_QUADS + 255) / 256, 256, 0, stream>>>(
        (const int4*)pred_sid, (const float4*)energy, (const int4*)rid, acc, R);
    // 3) replica reduce + per-shower correction + packing
    corr_kernel<<<(NUM_SEGMENTS + 255) / 256, 256, 0, stream>>>(
        pred_sid, pcf, a_tracks, a_hits, acc, R, vals);
    // 4) gather into the 4 output streams (float4 stores)
    gather_kernel<<<(N_QUADS + 255) / 256, 256, 0, stream>>>(
        (const int4*)pred_sid, vals, (float4*)d_out);
}

// Round 6
// 175.425 us; speedup vs baseline: 2.0816x; 1.9934x over previous
//
#include <hip/hip_runtime.h>

#define N_HITS 4000000
#define N_QUADS (N_HITS / 4)
#define N_SHOWERS 10000
#define NUM_SEGMENTS (N_SHOWERS + 1)
#define ACC_STRIDE (2 * NUM_SEGMENTS)      // 20002 floats: [hit | track]
#define R_BLOCKS 512                       // scatter blocks == replica count
#define G_PART 16                          // first-level reduction fan-in

// ---------------------------------------------------------------------------
// Scratch layout (NO ws_size assumptions beyond 160 KB, proven in rounds 1/5):
//   d_ws [0, 160016)                    : float4 vals[NUM_SEGMENTS]
//   d_out float-offset 0                : float acc [R_BLOCKS][ACC_STRIDE]
//   d_out float-offset 10,241,024       : float acc2[G_PART ][ACC_STRIDE]
// d_out (16M floats) is free scratch until gather_kernel overwrites all of it;
// acc/acc2 are consumed by reduce/corr BEFORE gather runs (same stream).
// ---------------------------------------------------------------------------
#define ACC2_OFF ((size_t)R_BLOCKS * ACC_STRIDE)   // 10,241,024 floats

__global__ __launch_bounds__(1024) void
scatter_kernel(const int4* __restrict__ sid4,
               const float4* __restrict__ e4,
               const int4* __restrict__ rid4,
               float* __restrict__ acc) {
    __shared__ float h[ACC_STRIDE];                 // 80,008 B; 2 blocks/CU
    for (int i = threadIdx.x; i < ACC_STRIDE; i += 1024) h[i] = 0.0f;
    __syncthreads();
    for (int t = blockIdx.x * 1024 + threadIdx.x; t < N_QUADS;
         t += R_BLOCKS * 1024) {
        int4   s = sid4[t];
        float4 e = e4[t];
        int4   r = rid4[t];
        // rid==0 -> hit half [0,NUM_SEGMENTS), rid==1 -> track half
        if (s.x >= 0) atomicAdd(&h[r.x * NUM_SEGMENTS + s.x + 1], e.x);
        if (s.y >= 0) atomicAdd(&h[r.y * NUM_SEGMENTS + s.y + 1], e.y);
        if (s.z >= 0) atomicAdd(&h[r.z * NUM_SEGMENTS + s.z + 1], e.z);
        if (s.w >= 0) atomicAdd(&h[r.w * NUM_SEGMENTS + s.w + 1], e.w);
    }
    __syncthreads();
    float* __restrict__ dst = acc + (size_t)blockIdx.x * ACC_STRIDE;
    for (int i = threadIdx.x; i < ACC_STRIDE; i += 1024) dst[i] = h[i];
}

__global__ void reduce_kernel(const float* __restrict__ acc,
                              float* __restrict__ acc2) {
    int s = blockIdx.x * 256 + threadIdx.x;         // column 0..ACC_STRIDE-1
    if (s >= ACC_STRIDE) return;
    int g = blockIdx.y;                             // partial group 0..G_PART-1
    float v = 0.0f;
    for (int r = g; r < R_BLOCKS; r += G_PART)      // 32 coalesced loads
        v += acc[(size_t)r * ACC_STRIDE + s];
    acc2[(size_t)g * ACC_STRIDE + s] = v;
}

__global__ void corr_kernel(const int* __restrict__ sid,
                            const float* __restrict__ pcf,
                            const int* __restrict__ a_tracks,
                            const int* __restrict__ a_hits,
                            const float* __restrict__ acc2,
                            float4* __restrict__ vals) {
    int s = blockIdx.x * 256 + threadIdx.x;         // segment 0..NUM_SEGMENTS-1
    if (s >= NUM_SEGMENTS) return;
    float eh = 0.0f, et = 0.0f;
    for (int g = 0; g < G_PART; ++g) {
        eh += acc2[(size_t)g * ACC_STRIDE + s];
        et += acc2[(size_t)g * ACC_STRIDE + NUM_SEGMENTS + s];
    }
    float ch = 0.0f, ct = 0.0f;
    if (s > 0) {
        int ih = a_hits[s - 1];                     // in [0, N_HITS]
        if (ih < N_HITS && sid[ih] != -1) ch = pcf[ih];
        int it = a_tracks[s - 1];
        if (it < N_HITS && sid[it] != -1) ct = pcf[it];
    }
    vals[s] = make_float4(et, et * ct, eh, eh * ch);
}

__global__ void gather_kernel(const int4* __restrict__ sid4,
                              const float4* __restrict__ vals,
                              float4* __restrict__ out) {
    int t = blockIdx.x * blockDim.x + threadIdx.x;
    if (t >= N_QUADS) return;
    int4 s = sid4[t];
    float4 a = vals[s.x + 1];
    float4 b = vals[s.y + 1];
    float4 c = vals[s.z + 1];
    float4 d = vals[s.w + 1];
    out[t]               = make_float4(a.x, b.x, c.x, d.x);  // e_track_raw
    out[N_QUADS + t]     = make_float4(a.y, b.y, c.y, d.y);  // e_track_corrected
    out[2 * N_QUADS + t] = make_float4(a.z, b.z, c.z, d.z);  // e_hit_raw
    out[3 * N_QUADS + t] = make_float4(a.w, b.w, c.w, d.w);  // e_hit_corrected
}

extern "C" void kernel_launch(void* const* d_in, const int* in_sizes, int n_in,
                              void* d_out, int out_size, void* d_ws, size_t ws_size,
                              hipStream_t stream) {
    const int*   pred_sid = (const int*)  d_in[0];
    const float* pcf      = (const float*)d_in[1];
    const float* energy   = (const float*)d_in[2];
    const int*   rid      = (const int*)  d_in[3];
    // d_in[4] = pred_beta (unused)
    const int*   a_tracks = (const int*)  d_in[5];
    const int*   a_hits   = (const int*)  d_in[6];

    float*  out_f = (float*)d_out;
    float*  acc   = out_f;                  // [R_BLOCKS][ACC_STRIDE] scratch
    float*  acc2  = out_f + ACC2_OFF;       // [G_PART][ACC_STRIDE] scratch
    float4* vals  = (float4*)d_ws;          // 160 KB, survives into gather

    // 1) LDS-privatized segment-sum -> 512 replicas (no global atomics)
    scatter_kernel<<<R_BLOCKS, 1024, 0, stream>>>(
        (const int4*)pred_sid, (const float4*)energy, (const int4*)rid, acc);
    // 2) replica tree-reduce 512 -> 16
    {
        dim3 grid((ACC_STRIDE + 255) / 256, G_PART);
        reduce_kernel<<<grid, 256, 0, stream>>>(acc, acc2);
    }
    // 3) 16 -> 1 + per-shower correction + packing
    corr_kernel<<<(NUM_SEGMENTS + 255) / 256, 256, 0, stream>>>(
        pred_sid, pcf, a_tracks, a_hits, acc2, vals);
    // 4) gather into the 4 output streams (overwrites ALL of d_out)
    gather_kernel<<<(N_QUADS + 1023) / 1024, 1024, 0, stream>>>(
        (const int4*)pred_sid, vals, (float4*)d_out);
}